// Round 7
// baseline (172.396 us; speedup 1.0000x reference)
//
#include <hip/hip_runtime.h>

// Lucas-Kanade optical flow v7 = v6 algorithm + forced 128-VGPR budget.
// Root cause of v3-v6 slowness: allocator targeted 8 waves/EU (64 VGPR) and
// spilled ~70 floats of row state to scratch (WRITE_SIZE 114-337 MB vs 34
// ideal). amdgpu_waves_per_eu(4,4) pins the tier: 4 waves/EU, 128 VGPRs.
// Structure: RB=4, 4608 one-wave blocks, XCD-chunked band swizzle; 19 row
// loads/block (exit rows pinned in registers, never reloaded); flat fully
// unrolled scan loop, shift-chain register renames.
// Derivatives unscaled (8fx, 8fy, 4ft); exact power-of-2 rescale (x2) folded
// into the final u,v.

constexpr int IH  = 2048;
constexpr int IW  = 2048;
constexpr int RAD = 7;
constexpr int WIN = 15;
constexpr int NT  = 64;              // 1 wave per block
constexpr int SW  = 240;             // output columns per block (lanes 0..59 store)
constexpr int RB  = 4;               // output rows per block
constexpr int SCAN  = RB + WIN - 1;  // 18 steps; source rows r0-7 .. r0+11
constexpr int NSTRIP = 9;
constexpr int NBAND  = IH / RB;      // 512
constexpr int NXCD   = 8;
constexpr int CHUNK  = NBAND / NXCD; // 64 bands per XCD per strip

// Per-row derived terms for this lane's 4 columns: sp = prev+next, dt = next-prev.
struct Row { float sp[4]; float dt[4]; };

template<bool YE>
__device__ __forceinline__ Row load_row(const float* __restrict__ P,
                                        const float* __restrict__ N,
                                        int row, int pcb, bool lload) {
    if constexpr (YE) row = row < 0 ? 0 : (row > IH - 1 ? IH - 1 : row);
    float4 q = make_float4(0.f, 0.f, 0.f, 0.f);
    float4 r = q;
    if (lload) {   // uniform-true for interior strips; masks OOB lanes on edges
        const size_t off = (size_t)row * IW + pcb;
        q = *reinterpret_cast<const float4*>(P + off);   // 16B aligned
        r = *reinterpret_cast<const float4*>(N + off);
    }
    Row R;
    R.sp[0] = q.x + r.x; R.dt[0] = r.x - q.x;
    R.sp[1] = q.y + r.y; R.dt[1] = r.y - q.y;
    R.sp[2] = q.z + r.z; R.dt[2] = r.z - q.z;
    R.sp[3] = q.w + r.w; R.dt[3] = r.w - q.w;
    return R;
}

// Add (SUB=false) or remove (SUB=true) product-row pair (A=row r, B=row r+1).
template<bool SUB, bool XE>
__device__ __forceinline__ void accum(float V[5][4], const Row& A, const Row& B,
                                      int t, float keep4, bool rep4) {
    float g[5], m[5], e[5];
    #pragma unroll
    for (int c = 0; c < 4; ++c) {
        g[c] = A.sp[c] + B.sp[c];   // -> 8*fx via horizontal diff
        m[c] = B.sp[c] - A.sp[c];   // -> 8*fy
        e[c] = A.dt[c] + B.dt[c];   // -> 4*ft
    }
    // col-4 terms = neighbor lane's col 0 (lane 63's wrap feeds only the
    // untracked product col; never read by a storing lane).
    float g4 = __shfl(g[0], t + 1);
    float m4 = __shfl(m[0], t + 1);
    float e4 = __shfl(e[0], t + 1);
    if constexpr (XE) {
        g4 = (rep4 ? g[3] : g4) * keep4;   // right edge: replicate; left: zero
        m4 = (rep4 ? m[3] : m4) * keep4;
        e4 = (rep4 ? e[3] : e4) * keep4;
    }
    g[4] = g4; m[4] = m4; e[4] = e4;
    #pragma unroll
    for (int c = 0; c < 4; ++c) {
        const float fx = g[c + 1] - g[c];
        const float fy = m[c] + m[c + 1];
        const float ft = e[c] + e[c + 1];
        if (!SUB) {
            V[0][c] += fx * fx; V[1][c] += fx * fy; V[2][c] += fy * fy;
            V[3][c] += fx * ft; V[4][c] += fy * ft;
        } else {
            V[0][c] -= fx * fx; V[1][c] -= fx * fy; V[2][c] -= fy * fy;
            V[3][c] -= fx * ft; V[4][c] -= fy * ft;
        }
    }
}

template<bool XE, bool YE>
__device__ __forceinline__ void lk_body(const float* __restrict__ P,
                                        const float* __restrict__ N,
                                        float* __restrict__ out,
                                        int c0, int r0, int t) {
    const int pcb = c0 - 8 + 4 * t;     // this lane's first tracked column
    bool  lload = true;
    float keep4 = 1.f;
    bool  rep4  = false;
    if constexpr (XE) {
        lload = (pcb >= 0) && (pcb + 3 < IW);  // full float4 in range
        keep4 = (pcb + 3 >= 0) ? 1.f : 0.f;    // lane's last col outside-left -> zero
        rep4  = (pcb + 4 >= IW);               // col-4 outside-right -> replicate
    }

    // pinned exit rows (also the first four pipeline rows)
    Row X0 = load_row<YE>(P, N, r0 - RAD + 0, pcb, lload);
    Row X1 = load_row<YE>(P, N, r0 - RAD + 1, pcb, lload);
    Row X2 = load_row<YE>(P, N, r0 - RAD + 2, pcb, lload);
    Row X3 = load_row<YE>(P, N, r0 - RAD + 3, pcb, lload);
    Row A = X0, B = X1, C = X2, D = X3;

    float V[5][4] = {};

    #pragma unroll
    for (int sr = 0; sr < SCAN; ++sr) {   // fully unrolled: sr is compile-time
        const int pr = r0 - RAD + sr;     // entering product row

        // prefetch rows[sr+4] = image row pr+4 (becomes B three steps out)
        Row nD;
        if (sr + 4 <= SCAN)
            nD = load_row<YE>(P, N, pr + 4, pcb, lload);

        // entering product-row pair (A=rows[sr], B=rows[sr+1])
        bool enter_ok = true;
        if constexpr (YE) enter_ok = (pr >= 0) && (pr < IH);
        if (enter_ok) accum<false, XE>(V, A, B, t, keep4, rep4);

        // exiting product-row pair: rows[sr-15], rows[sr-14] == pinned X's
        if (sr >= WIN) {
            bool exit_ok = true;
            if constexpr (YE) exit_ok = (pr - WIN) >= 0;
            if (exit_ok) {
                if (sr == 15) accum<true, XE>(V, X0, X1, t, keep4, rep4);
                if (sr == 16) accum<true, XE>(V, X1, X2, t, keep4, rep4);
                if (sr == 17) accum<true, XE>(V, X2, X3, t, keep4, rep4);
            }
        }

        // emit output row i = r0 + sr-14
        if (sr >= WIN - 1) {
            float a[5][4];
            #pragma unroll
            for (int p = 0; p < 5; ++p) {
                const float v0 = V[p][0], v1 = V[p][1], v2 = V[p][2], v3 = V[p][3];
                const float Pg = (v0 + v1) + (v2 + v3);
                const float S1 = __shfl(Pg, t + 1);
                const float S2 = __shfl(Pg, t + 2);
                const float S3 = __shfl(Pg, t + 3);
                const float q0 = __shfl(v0, t + 4);
                const float q1 = __shfl(v1, t + 4);
                const float q2 = __shfl(v2, t + 4);
                a[p][0] = ((Pg - v0) + S1) + (S2 + S3);
                a[p][1] = a[p][0] - v1 + q0;
                a[p][2] = a[p][1] - v2 + q1;
                a[p][3] = a[p][2] - v3 + q2;
            }
            const int i = r0 + (sr - (WIN - 1));
            const int x = c0 + 4 * t;
            if (4 * t < SW && x < IW) {
                float4 qu, qv;
                float* uo = &qu.x; float* vo = &qv.x;
                #pragma unroll
                for (int c = 0; c < 4; ++c) {
                    const float Axx = a[0][c], Axy = a[1][c], Ayy = a[2][c];
                    const float bx = a[3][c], by = a[4][c];
                    const float det = Axx * Ayy - Axy * Axy;
                    const float rd  = __builtin_amdgcn_rcpf(det) * 2.0f;  // fold scale
                    const bool  ok  = (det != 0.f);
                    uo[c] = ok ? (Ayy * bx - Axy * by) * rd : 0.f;
                    vo[c] = ok ? (Axx * by - Axy * bx) * rd : 0.f;
                }
                *reinterpret_cast<float4*>(out + (size_t)i * IW + x) = qu;
                *reinterpret_cast<float4*>(out + (size_t)IH * IW + (size_t)i * IW + x) = qv;
            }
        }

        // slide (register renames after unroll)
        A = B; B = C; C = D;
        if (sr + 4 <= SCAN) D = nD;
    }
}

__global__ __launch_bounds__(NT)
__attribute__((amdgpu_waves_per_eu(4, 4)))   // pin 4 waves/EU -> 128-VGPR budget, no spill-for-occupancy
void lk_kernel(const float* __restrict__ Pimg, const float* __restrict__ Nimg,
               float* __restrict__ out) {
    // XCD-chunked swizzle: XCD (bid&7) owns 64 contiguous 4-row bands of one
    // strip, so vertical-halo re-reads across adjacent bands hit the local L2.
    const int bid   = blockIdx.x;
    const int xcd   = bid & 7;
    const int idx   = bid >> 3;              // 0..575
    const int strip = idx / CHUNK;           // 0..8
    const int pos   = idx % CHUNK;
    const int band  = xcd * CHUNK + pos;     // 0..511
    const int c0 = strip * SW;
    const int r0 = band * RB;
    const int t  = threadIdx.x;
    const bool xe = (strip == 0) || (strip == NSTRIP - 1);
    const bool ye = (band < 2) || (band >= NBAND - 2);
    if (!xe && !ye)      lk_body<false, false>(Pimg, Nimg, out, c0, r0, t);
    else if (xe && !ye)  lk_body<true,  false>(Pimg, Nimg, out, c0, r0, t);
    else if (!xe)        lk_body<false, true >(Pimg, Nimg, out, c0, r0, t);
    else                 lk_body<true,  true >(Pimg, Nimg, out, c0, r0, t);
}

extern "C" void kernel_launch(void* const* d_in, const int* in_sizes, int n_in,
                              void* d_out, int out_size, void* d_ws, size_t ws_size,
                              hipStream_t stream) {
    (void)in_sizes; (void)n_in; (void)d_ws; (void)ws_size; (void)out_size;
    const float* prev = (const float*)d_in[0];
    const float* nxt  = (const float*)d_in[1];
    float* out        = (float*)d_out;
    dim3 grid(NSTRIP * NBAND);               // 4608 one-wave blocks
    dim3 block(NT);
    hipLaunchKernelGGL(lk_kernel, grid, block, 0, stream, prev, nxt, out);
}

// Round 8
// 33.168 us; speedup vs baseline: 5.1977x; 5.1977x over previous
//
#include <hip/hip_runtime.h>

// Lucas-Kanade optical flow v8.
// Lesson from v3-v7: the allocator refuses >64 VGPRs when any occupancy
// attribute is present, and spills (WRITE_SIZE 114-340 MB vs 33.5 ideal).
// Fix: 2 columns/lane halves row state (Row = 4 floats, V = 10 floats);
// total live ~50 floats fits the 64-VGPR tier with zero spill. Plain
// __launch_bounds__(64) only (v1/v2 empirically got 88/72 VGPRs with it).
// Structure: RB=8 rows/block, 19 strips x 256 bands = 4864 one-wave blocks,
// XCD-chunked band swizzle, reload-exit register pipeline (E0..E2 entering,
// X0..X2 exiting, ~2-step prefetch distance), horizontal 15-tap via wave
// shuffles. Derivatives unscaled (8fx, 8fy, 4ft); exact power-of-2 rescale
// (x2) folded into final u,v.

constexpr int IH  = 2048;
constexpr int IW  = 2048;
constexpr int RAD = 7;
constexpr int WIN = 15;
constexpr int NT  = 64;               // 1 wave per block
constexpr int SW  = 112;              // output columns per block (2/lane, lanes 0..55)
constexpr int RB  = 8;                // output rows per block
constexpr int SCAN = RB + WIN - 1;    // 22 steps; product rows r0-7 .. r0+14
constexpr int NSTRIP = 19;            // 19*112 = 2128 >= 2048
constexpr int NBAND  = IH / RB;       // 256
constexpr int NXCD   = 8;
constexpr int CHUNK  = NBAND / NXCD;  // 32 bands per XCD per strip

// Per-row derived terms for this lane's 2 columns: sp = prev+next, dt = next-prev.
struct Row { float sp0, sp1, dt0, dt1; };

template<bool YE>
__device__ __forceinline__ Row load_row(const float* __restrict__ P,
                                        const float* __restrict__ N,
                                        int row, int pcb, bool lload) {
    if constexpr (YE) row = row < 0 ? 0 : (row > IH - 1 ? IH - 1 : row);
    float2 q = make_float2(0.f, 0.f), r = q;
    if (lload) {                       // false only for OOB lanes on edge strips
        const size_t off = (size_t)row * IW + pcb;
        q = *reinterpret_cast<const float2*>(P + off);   // 8B aligned (pcb even)
        r = *reinterpret_cast<const float2*>(N + off);
    }
    Row R;
    R.sp0 = q.x + r.x; R.dt0 = r.x - q.x;
    R.sp1 = q.y + r.y; R.dt1 = r.y - q.y;
    return R;
}

// Add (SUB=false) or remove (SUB=true) product-row pair (A=row r, B=row r+1).
// Lane handles product cols pcb, pcb+1; col pcb+2 terms come from lane t+1.
template<bool SUB, bool XE>
__device__ __forceinline__ void accum(float V[5][2], const Row& A, const Row& B,
                                      int t, bool ok, bool rep2) {
    const float g0 = A.sp0 + B.sp0, g1 = A.sp1 + B.sp1;  // -> 8*fx via horiz diff
    const float m0 = B.sp0 - A.sp0, m1 = B.sp1 - A.sp1;  // -> 8*fy
    const float e0 = A.dt0 + B.dt0, e1 = A.dt1 + B.dt1;  // -> 4*ft
    float g2 = __shfl(g0, t + 1);
    float m2 = __shfl(m0, t + 1);
    float e2 = __shfl(e0, t + 1);
    if constexpr (XE) {                 // right edge: replicate last column
        g2 = rep2 ? g1 : g2; m2 = rep2 ? m1 : m2; e2 = rep2 ? e1 : e2;
    }
    float fx0 = g1 - g0, fy0 = m0 + m1, ft0 = e0 + e1;
    float fx1 = g2 - g1, fy1 = m1 + m2, ft1 = e1 + e2;
    if constexpr (XE) {                 // zero products outside the image
        fx0 = ok ? fx0 : 0.f; fy0 = ok ? fy0 : 0.f; ft0 = ok ? ft0 : 0.f;
        fx1 = ok ? fx1 : 0.f; fy1 = ok ? fy1 : 0.f; ft1 = ok ? ft1 : 0.f;
    }
    if constexpr (!SUB) {
        V[0][0] += fx0 * fx0; V[1][0] += fx0 * fy0; V[2][0] += fy0 * fy0;
        V[3][0] += fx0 * ft0; V[4][0] += fy0 * ft0;
        V[0][1] += fx1 * fx1; V[1][1] += fx1 * fy1; V[2][1] += fy1 * fy1;
        V[3][1] += fx1 * ft1; V[4][1] += fy1 * ft1;
    } else {
        V[0][0] -= fx0 * fx0; V[1][0] -= fx0 * fy0; V[2][0] -= fy0 * fy0;
        V[3][0] -= fx0 * ft0; V[4][0] -= fy0 * ft0;
        V[0][1] -= fx1 * fx1; V[1][1] -= fx1 * fy1; V[2][1] -= fy1 * fy1;
        V[3][1] -= fx1 * ft1; V[4][1] -= fy1 * ft1;
    }
}

template<bool XE, bool YE>
__device__ __forceinline__ void lk_body(const float* __restrict__ P,
                                        const float* __restrict__ N,
                                        float* __restrict__ out,
                                        int c0, int r0, int t) {
    const int pcb = c0 - 8 + 2 * t;     // lane's first tracked product column (even)
    bool ok = true, rep2 = false;
    if constexpr (XE) {
        ok   = ((unsigned)pcb < (unsigned)IW);   // both owned cols in image
        rep2 = (pcb + 2 >= IW) && ok;            // col pcb+2 replicates pcb+1
    }
    const bool lload = ok;              // interior strips: uniformly true

    float V[5][2] = {};

    // entering pipeline: E0=row pr, E1=pr+1, E2=pr+2 (prefetch distance 2)
    Row E0 = load_row<YE>(P, N, r0 - 7, pcb, lload);
    Row E1 = load_row<YE>(P, N, r0 - 6, pcb, lload);
    Row E2 = load_row<YE>(P, N, r0 - 5, pcb, lload);
    Row X0, X1, X2;                     // exiting pipeline (reloaded, L2-hot)

    #pragma unroll
    for (int sr = 0; sr < SCAN; ++sr) { // fully unrolled: sr compile-time
        const int pr = r0 - RAD + sr;   // entering product row

        // issue loads first
        Row nE, nX;
        const bool doE = (sr <= 19);    // row pr+3, last needed row = r0+15
        if (doE) nE = load_row<YE>(P, N, pr + 3, pcb, lload);
        const bool doX = (sr >= 12 && sr <= 19);  // rows r0-7 .. r0 (exit pairs)
        if (doX) nX = load_row<YE>(P, N, r0 + sr - 19, pcb, lload);

        // vertical running box sum: add entering product row
        bool enter_ok = true;
        if constexpr (YE) enter_ok = (pr >= 0) && (pr < IH);
        if (enter_ok) accum<false, XE>(V, E0, E1, t, ok, rep2);

        // subtract exiting product row (po = pr-15)
        if (sr >= 15) {
            bool exit_ok = true;
            if constexpr (YE) exit_ok = (pr - WIN) >= 0;
            if (exit_ok) accum<true, XE>(V, X0, X1, t, ok, rep2);
        }

        // emit output row i = r0 + sr - 14
        if (sr >= WIN - 1) {
            float a0[5], a1[5];
            #pragma unroll
            for (int p = 0; p < 5; ++p) {
                const float Pg = V[p][0] + V[p][1];       // pair sum
                float s = __shfl(Pg, t + 1);
                s += __shfl(Pg, t + 2); s += __shfl(Pg, t + 3);
                s += __shfl(Pg, t + 4); s += __shfl(Pg, t + 5);
                s += __shfl(Pg, t + 6); s += __shfl(Pg, t + 7);
                const float q0 = __shfl(V[p][0], t + 8);
                a0[p] = V[p][1] + s;    // window cols ci = 2t+1 .. 2t+15
                a1[p] = s + q0;         // window cols ci = 2t+2 .. 2t+16
            }
            const float det0 = a0[0] * a0[2] - a0[1] * a0[1];
            const float rd0  = __builtin_amdgcn_rcpf(det0) * 2.0f;  // fold scale
            const bool  k0   = (det0 != 0.f);
            const float det1 = a1[0] * a1[2] - a1[1] * a1[1];
            const float rd1  = __builtin_amdgcn_rcpf(det1) * 2.0f;
            const bool  k1   = (det1 != 0.f);
            float2 qu, qv;
            qu.x = k0 ? (a0[2] * a0[3] - a0[1] * a0[4]) * rd0 : 0.f;
            qv.x = k0 ? (a0[0] * a0[4] - a0[1] * a0[3]) * rd0 : 0.f;
            qu.y = k1 ? (a1[2] * a1[3] - a1[1] * a1[4]) * rd1 : 0.f;
            qv.y = k1 ? (a1[0] * a1[4] - a1[1] * a1[3]) * rd1 : 0.f;

            const int i  = r0 + sr - (WIN - 1);
            const int x0 = c0 + 2 * t;
            const bool st = (2 * t < SW) && (x0 < IW);    // x0 even -> x0+1 ok too
            if (st) {
                *reinterpret_cast<float2*>(out + (size_t)i * IW + x0) = qu;
                *reinterpret_cast<float2*>(out + (size_t)IH * IW + (size_t)i * IW + x0) = qv;
            }
        }

        // slides (register renames after full unroll)
        E0 = E1; E1 = E2; if (doE) E2 = nE;
        if (sr == 12)      X0 = nX;
        else if (sr == 13) X1 = nX;
        else if (sr == 14) X2 = nX;
        else if (sr >= 15) { X0 = X1; X1 = X2; if (doX) X2 = nX; }
    }
}

__global__ __launch_bounds__(NT)   // NO occupancy attrs: they pin VGPR=64 and spill
void lk_kernel(const float* __restrict__ Pimg, const float* __restrict__ Nimg,
               float* __restrict__ out) {
    // XCD-chunked swizzle: XCD (bid&7) owns 32 contiguous 8-row bands of one
    // strip -> vertical-halo re-reads hit the local L2. 4864 % 8 == 0.
    const int bid   = blockIdx.x;
    const int xcd   = bid & 7;
    const int idx   = bid >> 3;               // 0..607
    const int strip = idx / CHUNK;            // 0..18
    const int pos   = idx % CHUNK;
    const int band  = xcd * CHUNK + pos;      // 0..255
    const int c0 = strip * SW;
    const int r0 = band * RB;
    const int t  = threadIdx.x;
    const bool xe = (strip == 0) || (strip == NSTRIP - 1);
    const bool ye = (band == 0) || (band == NBAND - 1);
    if (!xe && !ye)      lk_body<false, false>(Pimg, Nimg, out, c0, r0, t);
    else if (xe && !ye)  lk_body<true,  false>(Pimg, Nimg, out, c0, r0, t);
    else if (!xe)        lk_body<false, true >(Pimg, Nimg, out, c0, r0, t);
    else                 lk_body<true,  true >(Pimg, Nimg, out, c0, r0, t);
}

extern "C" void kernel_launch(void* const* d_in, const int* in_sizes, int n_in,
                              void* d_out, int out_size, void* d_ws, size_t ws_size,
                              hipStream_t stream) {
    (void)in_sizes; (void)n_in; (void)d_ws; (void)ws_size; (void)out_size;
    const float* prev = (const float*)d_in[0];
    const float* nxt  = (const float*)d_in[1];
    float* out        = (float*)d_out;
    dim3 grid(NSTRIP * NBAND);                // 4864 one-wave blocks
    dim3 block(NT);
    hipLaunchKernelGGL(lk_kernel, grid, block, 0, stream, prev, nxt, out);
}

// Round 9
// 32.642 us; speedup vs baseline: 5.2814x; 1.0161x over previous
//
#include <hip/hip_runtime.h>

// Lucas-Kanade optical flow v9 = v8 + prefix-doubling emit tree + 4-wave WGs.
// v8 established: 2 cols/lane keeps total live state ~50 floats -> spill-free
// in the 64-VGPR tier (occupancy attrs pin VGPR=64 and spill; none used).
// v9 changes: (1) horizontal 15-tap window via shuffle prefix-doubling
// (4 shuffles + 7 VALU per plane vs 8+9 linear), (2) NT=256 with 4
// independent waves (one band each, no LDS/barriers) to dodge any
// workgroups-per-CU cap while keeping 4864 waves total.
// Derivatives unscaled (8fx, 8fy, 4ft); exact power-of-2 rescale (x2) folded
// into the final u,v.

constexpr int IH  = 2048;
constexpr int IW  = 2048;
constexpr int RAD = 7;
constexpr int WIN = 15;
constexpr int NT  = 256;              // 4 waves/block, each wave = one band
constexpr int SW  = 112;              // output columns per wave (2/lane, lanes 0..55)
constexpr int RB  = 8;                // output rows per band
constexpr int SCAN = RB + WIN - 1;    // 22 steps; product rows r0-7 .. r0+14
constexpr int NSTRIP = 19;            // 19*112 = 2128 >= 2048
constexpr int NBAND  = IH / RB;       // 256
constexpr int NGRP   = NBAND / 4;     // 64 band-groups (4 bands = 1 block)
constexpr int NXCD   = 8;
constexpr int CHUNK  = NGRP / NXCD;   // 8 groups per XCD per strip

// Per-row derived terms for this lane's 2 columns: sp = prev+next, dt = next-prev.
struct Row { float sp0, sp1, dt0, dt1; };

template<bool YE>
__device__ __forceinline__ Row load_row(const float* __restrict__ P,
                                        const float* __restrict__ N,
                                        int row, int pcb, bool lload) {
    if constexpr (YE) row = row < 0 ? 0 : (row > IH - 1 ? IH - 1 : row);
    float2 q = make_float2(0.f, 0.f), r = q;
    if (lload) {                       // false only for OOB lanes on edge strips
        const size_t off = (size_t)row * IW + pcb;
        q = *reinterpret_cast<const float2*>(P + off);   // 8B aligned (pcb even)
        r = *reinterpret_cast<const float2*>(N + off);
    }
    Row R;
    R.sp0 = q.x + r.x; R.dt0 = r.x - q.x;
    R.sp1 = q.y + r.y; R.dt1 = r.y - q.y;
    return R;
}

// Add (SUB=false) or remove (SUB=true) product-row pair (A=row r, B=row r+1).
// Lane handles product cols pcb, pcb+1; col pcb+2 terms come from lane t+1.
template<bool SUB, bool XE>
__device__ __forceinline__ void accum(float V[5][2], const Row& A, const Row& B,
                                      int t, bool ok, bool rep2) {
    const float g0 = A.sp0 + B.sp0, g1 = A.sp1 + B.sp1;  // -> 8*fx via horiz diff
    const float m0 = B.sp0 - A.sp0, m1 = B.sp1 - A.sp1;  // -> 8*fy
    const float e0 = A.dt0 + B.dt0, e1 = A.dt1 + B.dt1;  // -> 4*ft
    float g2 = __shfl(g0, t + 1);
    float m2 = __shfl(m0, t + 1);
    float e2 = __shfl(e0, t + 1);
    if constexpr (XE) {                 // right edge: replicate last column
        g2 = rep2 ? g1 : g2; m2 = rep2 ? m1 : m2; e2 = rep2 ? e1 : e2;
    }
    float fx0 = g1 - g0, fy0 = m0 + m1, ft0 = e0 + e1;
    float fx1 = g2 - g1, fy1 = m1 + m2, ft1 = e1 + e2;
    if constexpr (XE) {                 // zero products outside the image
        fx0 = ok ? fx0 : 0.f; fy0 = ok ? fy0 : 0.f; ft0 = ok ? ft0 : 0.f;
        fx1 = ok ? fx1 : 0.f; fy1 = ok ? fy1 : 0.f; ft1 = ok ? ft1 : 0.f;
    }
    if constexpr (!SUB) {
        V[0][0] += fx0 * fx0; V[1][0] += fx0 * fy0; V[2][0] += fy0 * fy0;
        V[3][0] += fx0 * ft0; V[4][0] += fy0 * ft0;
        V[0][1] += fx1 * fx1; V[1][1] += fx1 * fy1; V[2][1] += fy1 * fy1;
        V[3][1] += fx1 * ft1; V[4][1] += fy1 * ft1;
    } else {
        V[0][0] -= fx0 * fx0; V[1][0] -= fx0 * fy0; V[2][0] -= fy0 * fy0;
        V[3][0] -= fx0 * ft0; V[4][0] -= fy0 * ft0;
        V[0][1] -= fx1 * fx1; V[1][1] -= fx1 * fy1; V[2][1] -= fy1 * fy1;
        V[3][1] -= fx1 * ft1; V[4][1] -= fy1 * ft1;
    }
}

template<bool XE, bool YE>
__device__ __forceinline__ void lk_body(const float* __restrict__ P,
                                        const float* __restrict__ N,
                                        float* __restrict__ out,
                                        int c0, int r0, int t) {
    const int pcb = c0 - 8 + 2 * t;     // lane's first tracked product column (even)
    bool ok = true, rep2 = false;
    if constexpr (XE) {
        ok   = ((unsigned)pcb < (unsigned)IW);   // both owned cols in image
        rep2 = (pcb + 2 >= IW) && ok;            // col pcb+2 replicates pcb+1
    }
    const bool lload = ok;              // interior strips: uniformly true

    float V[5][2] = {};

    // entering pipeline: E0=row pr, E1=pr+1, E2=pr+2 (prefetch distance 2)
    Row E0 = load_row<YE>(P, N, r0 - 7, pcb, lload);
    Row E1 = load_row<YE>(P, N, r0 - 6, pcb, lload);
    Row E2 = load_row<YE>(P, N, r0 - 5, pcb, lload);
    Row X0, X1, X2;                     // exiting pipeline (reloaded, L2-hot)

    #pragma unroll
    for (int sr = 0; sr < SCAN; ++sr) { // fully unrolled: sr compile-time
        const int pr = r0 - RAD + sr;   // entering product row

        // issue loads first
        Row nE, nX;
        const bool doE = (sr <= 19);    // row pr+3, last needed row = r0+15
        if (doE) nE = load_row<YE>(P, N, pr + 3, pcb, lload);
        const bool doX = (sr >= 12 && sr <= 19);  // rows r0-7 .. r0 (exit pairs)
        if (doX) nX = load_row<YE>(P, N, r0 + sr - 19, pcb, lload);

        // vertical running box sum: add entering product row
        bool enter_ok = true;
        if constexpr (YE) enter_ok = (pr >= 0) && (pr < IH);
        if (enter_ok) accum<false, XE>(V, E0, E1, t, ok, rep2);

        // subtract exiting product row (po = pr-15)
        if (sr >= 15) {
            bool exit_ok = true;
            if constexpr (YE) exit_ok = (pr - WIN) >= 0;
            if (exit_ok) accum<true, XE>(V, X0, X1, t, ok, rep2);
        }

        // emit output row i = r0 + sr - 14
        if (sr >= WIN - 1) {
            // prefix-doubling window sums: S8(t) = sum of Pg over lanes t..t+7
            float a0[5], a1[5];
            #pragma unroll
            for (int p = 0; p < 5; ++p) {
                const float Pg = V[p][0] + V[p][1];        // pair sum (2 cols)
                float S = Pg + __shfl(Pg, t + 1);
                S += __shfl(S, t + 2);
                S += __shfl(S, t + 4);                     // 16-col sum, cols pcb..pcb+15
                const float q0 = __shfl(V[p][0], t + 8);   // col pcb+16
                a0[p] = S - V[p][0];                       // cols pcb+1 .. pcb+15
                a1[p] = (S - Pg) + q0;                     // cols pcb+2 .. pcb+16
            }
            const float det0 = a0[0] * a0[2] - a0[1] * a0[1];
            const float rd0  = __builtin_amdgcn_rcpf(det0) * 2.0f;  // fold scale
            const bool  k0   = (det0 != 0.f);
            const float det1 = a1[0] * a1[2] - a1[1] * a1[1];
            const float rd1  = __builtin_amdgcn_rcpf(det1) * 2.0f;
            const bool  k1   = (det1 != 0.f);
            float2 qu, qv;
            qu.x = k0 ? (a0[2] * a0[3] - a0[1] * a0[4]) * rd0 : 0.f;
            qv.x = k0 ? (a0[0] * a0[4] - a0[1] * a0[3]) * rd0 : 0.f;
            qu.y = k1 ? (a1[2] * a1[3] - a1[1] * a1[4]) * rd1 : 0.f;
            qv.y = k1 ? (a1[0] * a1[4] - a1[1] * a1[3]) * rd1 : 0.f;

            const int i  = r0 + sr - (WIN - 1);
            const int x0 = c0 + 2 * t;
            const bool st = (2 * t < SW) && (x0 < IW);    // x0 even -> x0+1 ok too
            if (st) {
                *reinterpret_cast<float2*>(out + (size_t)i * IW + x0) = qu;
                *reinterpret_cast<float2*>(out + (size_t)IH * IW + (size_t)i * IW + x0) = qv;
            }
        }

        // slides (register renames after full unroll)
        E0 = E1; E1 = E2; if (doE) E2 = nE;
        if (sr == 12)      X0 = nX;
        else if (sr == 13) X1 = nX;
        else if (sr == 14) X2 = nX;
        else if (sr >= 15) { X0 = X1; X1 = X2; if (doX) X2 = nX; }
    }
}

__global__ __launch_bounds__(NT)   // NO occupancy attrs: they pin VGPR=64 and spill
void lk_kernel(const float* __restrict__ Pimg, const float* __restrict__ Nimg,
               float* __restrict__ out) {
    // 4 independent waves per block (one 8-row band each; no LDS, no barriers).
    // XCD-chunked swizzle: XCD (bid&7) owns 8 contiguous 4-band groups of one
    // strip -> vertical-halo re-reads hit the local L2. 1216 % 8 == 0.
    const int bid   = blockIdx.x;
    const int xcd   = bid & 7;
    const int idx   = bid >> 3;               // 0..151
    const int strip = idx / CHUNK;            // 0..18
    const int pos   = idx % CHUNK;
    const int bg    = xcd * CHUNK + pos;      // 0..63 band-group within strip
    const int wid   = threadIdx.x >> 6;       // 0..3
    const int band  = bg * 4 + wid;           // 0..255
    const int t     = threadIdx.x & 63;
    const int c0 = strip * SW;
    const int r0 = band * RB;
    const bool xe = (strip == 0) || (strip == NSTRIP - 1);
    const bool ye = (band == 0) || (band == NBAND - 1);   // wave-uniform
    if (!xe && !ye)      lk_body<false, false>(Pimg, Nimg, out, c0, r0, t);
    else if (xe && !ye)  lk_body<true,  false>(Pimg, Nimg, out, c0, r0, t);
    else if (!xe)        lk_body<false, true >(Pimg, Nimg, out, c0, r0, t);
    else                 lk_body<true,  true >(Pimg, Nimg, out, c0, r0, t);
}

extern "C" void kernel_launch(void* const* d_in, const int* in_sizes, int n_in,
                              void* d_out, int out_size, void* d_ws, size_t ws_size,
                              hipStream_t stream) {
    (void)in_sizes; (void)n_in; (void)d_ws; (void)ws_size; (void)out_size;
    const float* prev = (const float*)d_in[0];
    const float* nxt  = (const float*)d_in[1];
    float* out        = (float*)d_out;
    dim3 grid(NSTRIP * NGRP);                 // 1216 blocks x 4 waves = 4864 waves
    dim3 block(NT);
    hipLaunchKernelGGL(lk_kernel, grid, block, 0, stream, prev, nxt, out);
}